// Round 1
// baseline (290.944 us; speedup 1.0000x reference)
//
#include <hip/hip_runtime.h>
#include <stdint.h>

// TMSA: two-stream multi-head causal self-attention, MI355X/gfx950.
// B=8 D=512 H=8 IMG=32 -> S=1024, DH=64.
// Pipeline:
//   1. convert: f32->bf16 pack Xcat[8192][1024], WcatT[1536][1024] (B^T), WoT[512][512]
//   2. gemm<0>: QKV = Xcat @ Wcat (epilogue scatters per-head, folds WK bias into K)
//   3. vtrans : V row-major -> VT [bh][d][s]
//   4. attn   : causal flash attention, 1 wave per 16 q-rows
//   5. gemm<1>: out = H @ Wo  (f32 epilogue straight to d_out)

typedef __bf16 bf16x8 __attribute__((ext_vector_type(8)));
typedef float  f32x4  __attribute__((ext_vector_type(4)));

#define DEVI __device__ __forceinline__

constexpr int Bc = 8, Dc = 512, Hc = 8, Sc = 1024, DHc = 64;
constexpr int Mc = Bc * Sc;          // 8192 rows
constexpr int NXc = Mc * 1024;       // Xcat elems  8388608
constexpr int NWc = 1536 * 1024;     // WcatT elems 1572864
constexpr int NOc = 512 * 512;       // WoT elems    262144

DEVI unsigned short f2b(float f) {           // f32 -> bf16, round-nearest-even
  union { float f; unsigned u; } v; v.f = f;
  unsigned u = v.u;
  return (unsigned short)((u + 0x7FFFu + ((u >> 16) & 1u)) >> 16);
}

// ---------------------------------------------------------------- stage 1
__global__ __launch_bounds__(256) void convert_kernel(
    const float* __restrict__ xs, const float* __restrict__ xt,
    const float* __restrict__ Wqs, const float* __restrict__ Wks, const float* __restrict__ Wvs,
    const float* __restrict__ Wqt, const float* __restrict__ Wkt, const float* __restrict__ Wvt,
    const float* __restrict__ Wo,
    unsigned short* __restrict__ Xcat, unsigned short* __restrict__ WcatT,
    unsigned short* __restrict__ WoT)
{
  int idx = blockIdx.x * 256 + threadIdx.x;
  if (idx < NXc) {
    // Xcat[m][c]: c<512 from xs (raw view [B,S,D]), else xt
    int m = idx >> 10, c = idx & 1023;
    float v = (c < 512) ? xs[(size_t)m * 512 + c] : xt[(size_t)m * 512 + (c - 512)];
    Xcat[idx] = f2b(v);
  } else if (idx < NXc + NWc) {
    // WcatT[n][k] = Wcat[k][n]; n: [Q|K|V] sections of 512, k: [spatial|temporal] halves
    int j = idx - NXc;
    int n = j >> 10, k = j & 1023;
    int sec = n >> 9, col = n & 511;
    const float* Ws = (sec == 0) ? Wqs : (sec == 1) ? Wks : Wvs;
    const float* Wt = (sec == 0) ? Wqt : (sec == 1) ? Wkt : Wvt;
    float v = (k < 512) ? Ws[(size_t)k * 512 + col] : Wt[(size_t)(k - 512) * 512 + col];
    WcatT[j] = f2b(v);
  } else {
    int j = idx - NXc - NWc;
    int n = j >> 9, k = j & 511;
    WoT[j] = f2b(Wo[(size_t)k * 512 + n]);
  }
}

// ---------------------------------------------------------------- GEMM (A row-major [M,K], BT row-major [N,K])
// 128x128 tile, BK=32, 256 threads = 4 waves in 2x2, each wave 64x64 via 4x4 frags of 16x16x32.
template <int EPI>
__global__ __launch_bounds__(256) void gemm_bt(
    const unsigned short* __restrict__ A, const unsigned short* __restrict__ BT, int K,
    float* __restrict__ Out, const float* __restrict__ WK,
    unsigned short* __restrict__ Qb, unsigned short* __restrict__ Kb,
    unsigned short* __restrict__ Vb)
{
  __shared__ unsigned short As[128 * 32];
  __shared__ unsigned short Bs[128 * 32];
  const int t = threadIdx.x;
  const int lane = t & 63, wid = t >> 6;
  const int wr = wid >> 1, wc = wid & 1;
  const int mtile = blockIdx.x, ntile = blockIdx.y;
  const int arow = t >> 2, acol = (t & 3) << 3;   // staging: row within 64-row half, col (8 elems)
  const int li = lane & 15, g = lane >> 4;

  f32x4 acc[4][4];
#pragma unroll
  for (int i = 0; i < 4; i++)
#pragma unroll
    for (int j = 0; j < 4; j++) acc[i][j] = (f32x4){0.f, 0.f, 0.f, 0.f};

  const unsigned short* aBase = A + (size_t)(mtile * 128 + arow) * K + acol;
  const unsigned short* bBase = BT + (size_t)(ntile * 128 + arow) * K + acol;

  for (int k0 = 0; k0 < K; k0 += 32) {
    // global -> LDS direct, 16B/lane, linear dest (wave-uniform base + lane*16)
    __builtin_amdgcn_global_load_lds(
        (__attribute__((address_space(1))) void*)(aBase + k0),
        (__attribute__((address_space(3))) void*)&As[wid * 512], 16, 0, 0);
    __builtin_amdgcn_global_load_lds(
        (__attribute__((address_space(1))) void*)(aBase + (size_t)64 * K + k0),
        (__attribute__((address_space(3))) void*)&As[2048 + wid * 512], 16, 0, 0);
    __builtin_amdgcn_global_load_lds(
        (__attribute__((address_space(1))) void*)(bBase + k0),
        (__attribute__((address_space(3))) void*)&Bs[wid * 512], 16, 0, 0);
    __builtin_amdgcn_global_load_lds(
        (__attribute__((address_space(1))) void*)(bBase + (size_t)64 * K + k0),
        (__attribute__((address_space(3))) void*)&Bs[2048 + wid * 512], 16, 0, 0);
    __syncthreads();

    bf16x8 af[4], bfr[4];
#pragma unroll
    for (int fi = 0; fi < 4; fi++)
      af[fi] = *(const bf16x8*)&As[(wr * 64 + fi * 16 + li) * 32 + (g << 3)];
#pragma unroll
    for (int fj = 0; fj < 4; fj++)
      bfr[fj] = *(const bf16x8*)&Bs[(wc * 64 + fj * 16 + li) * 32 + (g << 3)];
#pragma unroll
    for (int fi = 0; fi < 4; fi++)
#pragma unroll
      for (int fj = 0; fj < 4; fj++)
        acc[fi][fj] = __builtin_amdgcn_mfma_f32_16x16x32_bf16(af[fi], bfr[fj], acc[fi][fj], 0, 0, 0);
    __syncthreads();
  }

  const int lm = g << 2;
  if constexpr (EPI == 0) {
    // scatter into per-head Q/K'/V (K' += WK bias), bf16
#pragma unroll
    for (int fi = 0; fi < 4; fi++) {
      int mg = mtile * 128 + wr * 64 + fi * 16 + lm;
#pragma unroll
      for (int r = 0; r < 4; r++) {
        int m = mg + r;
        int b = m >> 10, s = m & 1023;
#pragma unroll
        for (int fj = 0; fj < 4; fj++) {
          int n = ntile * 128 + wc * 64 + fj * 16 + li;
          float v = acc[fi][fj][r];
          int sec = n >> 9, nn = n & 511;
          int h = nn >> 6, d = nn & 63;
          size_t o = ((size_t)(b * 8 + h) << 16) + (size_t)s * 64 + d;
          if (sec == 0)      Qb[o] = f2b(v);
          else if (sec == 1) Kb[o] = f2b(v + WK[(size_t)d * 1024 + s]);
          else               Vb[o] = f2b(v);
        }
      }
    }
  } else {
    // plain f32 epilogue, N = 512
#pragma unroll
    for (int fi = 0; fi < 4; fi++) {
      int mg = mtile * 128 + wr * 64 + fi * 16 + lm;
#pragma unroll
      for (int r = 0; r < 4; r++) {
        size_t m = (size_t)(mg + r);
#pragma unroll
        for (int fj = 0; fj < 4; fj++) {
          int n = ntile * 128 + wc * 64 + fj * 16 + li;
          Out[m * 512 + n] = acc[fi][fj][r];
        }
      }
    }
  }
}

// ---------------------------------------------------------------- stage 3: V [bh][s][d] -> VT [bh][d][s]
__global__ __launch_bounds__(256) void vtrans_kernel(const unsigned short* __restrict__ Vrm,
                                                     unsigned short* __restrict__ VT)
{
  __shared__ unsigned short tile[64][65];
  const int bh = blockIdx.y, st = blockIdx.x;
  const unsigned short* src = Vrm + (size_t)bh * 65536 + (size_t)st * 64 * 64;
#pragma unroll
  for (int i = 0; i < 16; i++) {
    int idx = i * 256 + threadIdx.x;
    tile[idx >> 6][idx & 63] = src[idx];
  }
  __syncthreads();
  unsigned short* dst = VT + (size_t)bh * 65536 + st * 64;
#pragma unroll
  for (int i = 0; i < 16; i++) {
    int idx = i * 256 + threadIdx.x;
    int dl = idx >> 6, s = idx & 63;
    dst[(size_t)dl * 1024 + s] = tile[s][dl];
  }
}

// ---------------------------------------------------------------- stage 4: causal flash attention
// 1 wave per block; 16 q-rows per wave; kv chunks of 64. K/V read from global (L2-resident).
__global__ __launch_bounds__(64) void attn_kernel(
    const unsigned short* __restrict__ Q, const unsigned short* __restrict__ Kp,
    const unsigned short* __restrict__ VT, unsigned short* __restrict__ Hout)
{
  __shared__ unsigned short P_lds[2][16 * 64];
  const int lane = threadIdx.x;
  const int qi = (int)(gridDim.x - 1) - (int)blockIdx.x;  // heaviest q-tiles dispatch first
  const int bh = blockIdx.y;
  const int b = bh >> 3, h = bh & 7;
  const int qbase = qi * 16;
  const int g = lane >> 4, li = lane & 15;
  const float L2E = 1.44269504088896340736f;

  const unsigned short* Qrow = Q + ((size_t)bh * 1024 + qbase) * 64;
  bf16x8 aq0 = *(const bf16x8*)&Qrow[li * 64 + (g << 3)];
  bf16x8 aq1 = *(const bf16x8*)&Qrow[li * 64 + 32 + (g << 3)];

  f32x4 hacc[4];
#pragma unroll
  for (int fj = 0; fj < 4; fj++) hacc[fj] = (f32x4){0.f, 0.f, 0.f, 0.f};
  float mrow[4] = {-1e30f, -1e30f, -1e30f, -1e30f};
  float lrow[4] = {0.f, 0.f, 0.f, 0.f};

  const int nchunk = qbase / 64 + 1;
  for (int c = 0; c < nchunk; ++c) {
    const int kv = c * 64;
    const unsigned short* Krow = Kp + ((size_t)bh * 1024 + kv) * 64;

    f32x4 sc[4];
#pragma unroll
    for (int tt = 0; tt < 4; tt++) {
      bf16x8 bk0 = *(const bf16x8*)&Krow[(tt * 16 + li) * 64 + (g << 3)];
      bf16x8 bk1 = *(const bf16x8*)&Krow[(tt * 16 + li) * 64 + 32 + (g << 3)];
      f32x4 z = (f32x4){0.f, 0.f, 0.f, 0.f};
      z = __builtin_amdgcn_mfma_f32_16x16x32_bf16(aq0, bk0, z, 0, 0, 0);
      z = __builtin_amdgcn_mfma_f32_16x16x32_bf16(aq1, bk1, z, 0, 0, 0);
      sc[tt] = z;
    }

    // scale, causal mask, per-row max (rows live in one 16-lane group; reg r = row g*4+r)
    float rm[4] = {-1e30f, -1e30f, -1e30f, -1e30f};
#pragma unroll
    for (int tt = 0; tt < 4; tt++) {
      int kpos = kv + tt * 16 + li;
#pragma unroll
      for (int r = 0; r < 4; r++) {
        int q = qbase + (g << 2) + r;
        float sv = sc[tt][r] * 0.125f;
        sv = (kpos <= q) ? sv : -1e30f;
        sc[tt][r] = sv;
        rm[r] = fmaxf(rm[r], sv);
      }
    }
#pragma unroll
    for (int msk = 1; msk < 16; msk <<= 1)
#pragma unroll
      for (int r = 0; r < 4; r++) rm[r] = fmaxf(rm[r], __shfl_xor(rm[r], msk, 64));

    float scl[4];
#pragma unroll
    for (int r = 0; r < 4; r++) {
      float mn = fmaxf(mrow[r], rm[r]);
      scl[r] = exp2f((mrow[r] - mn) * L2E);
      mrow[r] = mn;
      lrow[r] *= scl[r];
    }
#pragma unroll
    for (int fj = 0; fj < 4; fj++)
#pragma unroll
      for (int r = 0; r < 4; r++) hacc[fj][r] *= scl[r];

    unsigned short* pb = &P_lds[c & 1][0];
    float ps[4] = {0.f, 0.f, 0.f, 0.f};
#pragma unroll
    for (int tt = 0; tt < 4; tt++)
#pragma unroll
      for (int r = 0; r < 4; r++) {
        float p = exp2f((sc[tt][r] - mrow[r]) * L2E);
        ps[r] += p;
        pb[((g << 2) + r) * 64 + tt * 16 + li] = f2b(p);
      }
#pragma unroll
    for (int msk = 1; msk < 16; msk <<= 1)
#pragma unroll
      for (int r = 0; r < 4; r++) ps[r] += __shfl_xor(ps[r], msk, 64);
#pragma unroll
    for (int r = 0; r < 4; r++) lrow[r] += ps[r];

    // cross-lane LDS transpose hazard: drain ds_writes before fragment reads
    asm volatile("s_waitcnt lgkmcnt(0)" ::: "memory");
    __builtin_amdgcn_sched_barrier(0);

    bf16x8 ap0 = *(const bf16x8*)&pb[li * 64 + (g << 3)];
    bf16x8 ap1 = *(const bf16x8*)&pb[li * 64 + 32 + (g << 3)];
    const unsigned short* Vrow = VT + (size_t)bh * 65536 + kv;
#pragma unroll
    for (int fj = 0; fj < 4; fj++) {
      bf16x8 bv0 = *(const bf16x8*)&Vrow[(fj * 16 + li) * 1024 + (g << 3)];
      bf16x8 bv1 = *(const bf16x8*)&Vrow[(fj * 16 + li) * 1024 + 32 + (g << 3)];
      hacc[fj] = __builtin_amdgcn_mfma_f32_16x16x32_bf16(ap0, bv0, hacc[fj], 0, 0, 0);
      hacc[fj] = __builtin_amdgcn_mfma_f32_16x16x32_bf16(ap1, bv1, hacc[fj], 0, 0, 0);
    }
  }

  float inv[4];
#pragma unroll
  for (int r = 0; r < 4; r++) inv[r] = 1.0f / lrow[r];
#pragma unroll
  for (int fj = 0; fj < 4; fj++)
#pragma unroll
    for (int r = 0; r < 4; r++) {
      int q = qbase + (g << 2) + r;
      float v = hacc[fj][r] * inv[r];
      Hout[((size_t)b * 1024 + q) * 512 + h * 64 + fj * 16 + li] = f2b(v);
    }
}

// ---------------------------------------------------------------- launch
extern "C" void kernel_launch(void* const* d_in, const int* in_sizes, int n_in,
                              void* d_out, int out_size, void* d_ws, size_t ws_size,
                              hipStream_t stream)
{
  const float* xs  = (const float*)d_in[0];
  const float* xt  = (const float*)d_in[1];
  const float* Wqs = (const float*)d_in[2];
  const float* Wks = (const float*)d_in[3];
  const float* Wvs = (const float*)d_in[4];
  const float* Wqt = (const float*)d_in[5];
  const float* Wkt = (const float*)d_in[6];
  const float* Wvt = (const float*)d_in[7];
  const float* WK  = (const float*)d_in[8];
  const float* Wo  = (const float*)d_in[9];
  float* out = (float*)d_out;

  char* ws = (char*)d_ws;
  unsigned short* Xcat  = (unsigned short*)(ws);             // 16,777,216 B
  unsigned short* WcatT = (unsigned short*)(ws + 16777216);  //  3,145,728 B
  unsigned short* WoT   = (unsigned short*)(ws + 19922944);  //    524,288 B
  unsigned short* Qb    = (unsigned short*)(ws + 20447232);  //  8,388,608 B
  unsigned short* Kb    = (unsigned short*)(ws + 28835840);  //  8,388,608 B
  unsigned short* Vrm   = (unsigned short*)(ws + 37224448);  //  8,388,608 B
  unsigned short* VT    = (unsigned short*)(ws + 45613056);  //  8,388,608 B
  unsigned short* Hout  = (unsigned short*)(ws + 54001664);  //  8,388,608 B  (total 62,390,272)

  convert_kernel<<<39936, 256, 0, stream>>>(xs, xt, Wqs, Wks, Wvs, Wqt, Wkt, Wvt, Wo,
                                            Xcat, WcatT, WoT);
  gemm_bt<0><<<dim3(64, 12), 256, 0, stream>>>(Xcat, WcatT, 1024, nullptr, WK, Qb, Kb, Vrm);
  vtrans_kernel<<<dim3(16, 64), 256, 0, stream>>>(Vrm, VT);
  attn_kernel<<<dim3(64, 64), 64, 0, stream>>>(Qb, Kb, VT, Hout);
  gemm_bt<1><<<dim3(64, 4), 256, 0, stream>>>(Hout, WoT, 512, out, nullptr, nullptr, nullptr, nullptr);
}

// Round 2
// 276.062 us; speedup vs baseline: 1.0539x; 1.0539x over previous
//
#include <hip/hip_runtime.h>
#include <stdint.h>

// TMSA: two-stream multi-head causal self-attention, MI355X/gfx950.
// B=8 D=512 H=8 IMG=32 -> S=1024, DH=64.
// Pipeline:
//   1a. xconvert: f32->bf16 vectorized pack Xcat[8192][1024]
//   1b. wtrans  : LDS-tiled transposes -> WcatT[1536][1024] bf16, WoT[512][512] bf16,
//                 WKT[1024][64] f32 (so the K-bias epilogue read is coalesced)
//   2.  gemm<0> : QKV = Xcat @ Wcat (epilogue scatters per-head, folds WK bias into K)
//   3.  vtrans  : V row-major -> VT [bh][d][s]
//   4.  attn    : causal flash attention, 4 waves/block share K/V chunks (L1 reuse),
//                 padded P-LDS (conflict-free), V loads + next-K prefetch pipelined
//   5.  gemm<1> : out = H @ Wo (f32 epilogue straight to d_out). Hout aliases Xcat.

typedef __bf16 bf16x8 __attribute__((ext_vector_type(8)));
typedef float  f32x4  __attribute__((ext_vector_type(4)));
typedef unsigned short u16x8 __attribute__((ext_vector_type(8)));

#define DEVI __device__ __forceinline__

constexpr int Mc = 8 * 1024;         // 8192 rows

DEVI unsigned short f2b(float f) {           // f32 -> bf16, round-nearest-even
  union { float f; unsigned u; } v; v.f = f;
  unsigned u = v.u;
  return (unsigned short)((u + 0x7FFFu + ((u >> 16) & 1u)) >> 16);
}

// ---------------------------------------------------------------- stage 1a: X pack (vectorized)
__global__ __launch_bounds__(256) void xconvert_kernel(
    const float* __restrict__ xs, const float* __restrict__ xt,
    unsigned short* __restrict__ Xcat)
{
  int gid = blockIdx.x * 256 + threadIdx.x;       // 1048576 threads, 8 elems each
  int m = gid >> 7, c0 = (gid & 127) << 3;
  const float* src = (c0 < 512) ? xs + (size_t)m * 512 + c0
                                : xt + (size_t)m * 512 + (c0 - 512);
  float4 a = *(const float4*)src;
  float4 b = *(const float4*)(src + 4);
  u16x8 o;
  o[0] = f2b(a.x); o[1] = f2b(a.y); o[2] = f2b(a.z); o[3] = f2b(a.w);
  o[4] = f2b(b.x); o[5] = f2b(b.y); o[6] = f2b(b.z); o[7] = f2b(b.w);
  *(u16x8*)&Xcat[(size_t)m * 1024 + c0] = o;
}

// ---------------------------------------------------------------- stage 1b: weight transposes
__global__ __launch_bounds__(256) void wtrans_kernel(
    const float* __restrict__ Wqs, const float* __restrict__ Wks, const float* __restrict__ Wvs,
    const float* __restrict__ Wqt, const float* __restrict__ Wkt, const float* __restrict__ Wvt,
    const float* __restrict__ Wo,  const float* __restrict__ WK,
    unsigned short* __restrict__ WcatT, unsigned short* __restrict__ WoT,
    float* __restrict__ WKT)
{
  __shared__ __align__(16) char lds_raw[64 * 65 * 4];   // 16640 B, reused by both layouts
  const int t = threadIdx.x;
  const int r = t >> 2, cb = (t & 3) << 4;              // 64 rows x 4 col-blocks of 16
  const int mat = blockIdx.z;

  if (mat < 6) {
    // ordering: sec = mat>>1 (Q,K,V), half = mat&1 (spatial,temporal)
    const float* W = (mat == 0) ? Wqs : (mat == 1) ? Wqt : (mat == 2) ? Wks
                   : (mat == 3) ? Wkt : (mat == 4) ? Wvs : Wvt;
    const int ktile = blockIdx.x, ctile = blockIdx.y;
    unsigned short (*tile)[66] = (unsigned short (*)[66])lds_raw;
    const float* src = W + (size_t)(ktile * 64 + r) * 512 + ctile * 64 + cb;
#pragma unroll
    for (int i = 0; i < 4; i++) {
      float4 v = *(const float4*)(src + i * 4);
      tile[r][cb + i * 4 + 0] = f2b(v.x); tile[r][cb + i * 4 + 1] = f2b(v.y);
      tile[r][cb + i * 4 + 2] = f2b(v.z); tile[r][cb + i * 4 + 3] = f2b(v.w);
    }
    __syncthreads();
    const int n = ctile * 64 + r;
    const int sec = mat >> 1, half = mat & 1;
    u16x8 o0, o1;
#pragma unroll
    for (int i = 0; i < 8; i++) { o0[i] = tile[cb + i][r]; o1[i] = tile[cb + 8 + i][r]; }
    unsigned short* dst = WcatT + (size_t)(sec * 512 + n) * 1024 + half * 512 + ktile * 64 + cb;
    *(u16x8*)dst = o0; *(u16x8*)(dst + 8) = o1;
  } else if (mat == 6) {
    // Wo [512][512] -> WoT[n][k]
    const int ktile = blockIdx.x, ctile = blockIdx.y;
    unsigned short (*tile)[66] = (unsigned short (*)[66])lds_raw;
    const float* src = Wo + (size_t)(ktile * 64 + r) * 512 + ctile * 64 + cb;
#pragma unroll
    for (int i = 0; i < 4; i++) {
      float4 v = *(const float4*)(src + i * 4);
      tile[r][cb + i * 4 + 0] = f2b(v.x); tile[r][cb + i * 4 + 1] = f2b(v.y);
      tile[r][cb + i * 4 + 2] = f2b(v.z); tile[r][cb + i * 4 + 3] = f2b(v.w);
    }
    __syncthreads();
    const int n = ctile * 64 + r;
    u16x8 o0, o1;
#pragma unroll
    for (int i = 0; i < 8; i++) { o0[i] = tile[cb + i][r]; o1[i] = tile[cb + 8 + i][r]; }
    unsigned short* dst = WoT + (size_t)n * 512 + ktile * 64 + cb;
    *(u16x8*)dst = o0; *(u16x8*)(dst + 8) = o1;
  } else {
    // WK [64][1024] f32 -> WKT [1024][64] f32 (16 s-tiles)
    const int st = blockIdx.y * 8 + blockIdx.x;
    if (st >= 16) return;
    float (*tf)[65] = (float (*)[65])lds_raw;
    const float* src = WK + (size_t)r * 1024 + st * 64 + cb;   // r = d
#pragma unroll
    for (int i = 0; i < 4; i++) {
      float4 v = *(const float4*)(src + i * 4);
      tf[r][cb + i * 4 + 0] = v.x; tf[r][cb + i * 4 + 1] = v.y;
      tf[r][cb + i * 4 + 2] = v.z; tf[r][cb + i * 4 + 3] = v.w;
    }
    __syncthreads();
    const int s = st * 64 + r;
    float* dst = WKT + (size_t)s * 64 + cb;
#pragma unroll
    for (int i = 0; i < 4; i++) {
      float4 v;
      v.x = tf[cb + i * 4 + 0][r]; v.y = tf[cb + i * 4 + 1][r];
      v.z = tf[cb + i * 4 + 2][r]; v.w = tf[cb + i * 4 + 3][r];
      *(float4*)(dst + i * 4) = v;
    }
  }
}

// ---------------------------------------------------------------- GEMM (A row-major [M,K], BT row-major [N,K])
// 128x128 tile, BK=32, 256 threads = 4 waves in 2x2, each wave 64x64 via 4x4 frags of 16x16x32.
template <int EPI>
__global__ __launch_bounds__(256) void gemm_bt(
    const unsigned short* __restrict__ A, const unsigned short* __restrict__ BT, int K,
    float* __restrict__ Out, const float* __restrict__ WKT,
    unsigned short* __restrict__ Qb, unsigned short* __restrict__ Kb,
    unsigned short* __restrict__ Vb)
{
  __shared__ unsigned short As[128 * 32];
  __shared__ unsigned short Bs[128 * 32];
  const int t = threadIdx.x;
  const int lane = t & 63, wid = t >> 6;
  const int wr = wid >> 1, wc = wid & 1;
  const int mtile = blockIdx.x, ntile = blockIdx.y;
  const int arow = t >> 2, acol = (t & 3) << 3;
  const int li = lane & 15, g = lane >> 4;

  f32x4 acc[4][4];
#pragma unroll
  for (int i = 0; i < 4; i++)
#pragma unroll
    for (int j = 0; j < 4; j++) acc[i][j] = (f32x4){0.f, 0.f, 0.f, 0.f};

  const unsigned short* aBase = A + (size_t)(mtile * 128 + arow) * K + acol;
  const unsigned short* bBase = BT + (size_t)(ntile * 128 + arow) * K + acol;

  for (int k0 = 0; k0 < K; k0 += 32) {
    __builtin_amdgcn_global_load_lds(
        (__attribute__((address_space(1))) void*)(aBase + k0),
        (__attribute__((address_space(3))) void*)&As[wid * 512], 16, 0, 0);
    __builtin_amdgcn_global_load_lds(
        (__attribute__((address_space(1))) void*)(aBase + (size_t)64 * K + k0),
        (__attribute__((address_space(3))) void*)&As[2048 + wid * 512], 16, 0, 0);
    __builtin_amdgcn_global_load_lds(
        (__attribute__((address_space(1))) void*)(bBase + k0),
        (__attribute__((address_space(3))) void*)&Bs[wid * 512], 16, 0, 0);
    __builtin_amdgcn_global_load_lds(
        (__attribute__((address_space(1))) void*)(bBase + (size_t)64 * K + k0),
        (__attribute__((address_space(3))) void*)&Bs[2048 + wid * 512], 16, 0, 0);
    __syncthreads();

    bf16x8 af[4], bfr[4];
#pragma unroll
    for (int fi = 0; fi < 4; fi++)
      af[fi] = *(const bf16x8*)&As[(wr * 64 + fi * 16 + li) * 32 + (g << 3)];
#pragma unroll
    for (int fj = 0; fj < 4; fj++)
      bfr[fj] = *(const bf16x8*)&Bs[(wc * 64 + fj * 16 + li) * 32 + (g << 3)];
#pragma unroll
    for (int fi = 0; fi < 4; fi++)
#pragma unroll
      for (int fj = 0; fj < 4; fj++)
        acc[fi][fj] = __builtin_amdgcn_mfma_f32_16x16x32_bf16(af[fi], bfr[fj], acc[fi][fj], 0, 0, 0);
    __syncthreads();
  }

  const int lm = g << 2;
  if constexpr (EPI == 0) {
#pragma unroll
    for (int fi = 0; fi < 4; fi++) {
      int mg = mtile * 128 + wr * 64 + fi * 16 + lm;
#pragma unroll
      for (int r = 0; r < 4; r++) {
        int m = mg + r;
        int b = m >> 10, s = m & 1023;
#pragma unroll
        for (int fj = 0; fj < 4; fj++) {
          int n = ntile * 128 + wc * 64 + fj * 16 + li;
          float v = acc[fi][fj][r];
          int sec = n >> 9, nn = n & 511;
          int h = nn >> 6, d = nn & 63;
          size_t o = ((size_t)(b * 8 + h) << 16) + (size_t)s * 64 + d;
          if (sec == 0)      Qb[o] = f2b(v);
          else if (sec == 1) Kb[o] = f2b(v + WKT[(size_t)s * 64 + d]);
          else               Vb[o] = f2b(v);
        }
      }
    }
  } else {
#pragma unroll
    for (int fi = 0; fi < 4; fi++) {
      int mg = mtile * 128 + wr * 64 + fi * 16 + lm;
#pragma unroll
      for (int r = 0; r < 4; r++) {
        size_t m = (size_t)(mg + r);
#pragma unroll
        for (int fj = 0; fj < 4; fj++) {
          int n = ntile * 128 + wc * 64 + fj * 16 + li;
          Out[m * 512 + n] = acc[fi][fj][r];
        }
      }
    }
  }
}

// ---------------------------------------------------------------- stage 3: V [bh][s][d] -> VT [bh][d][s]
__global__ __launch_bounds__(256) void vtrans_kernel(const unsigned short* __restrict__ Vrm,
                                                     unsigned short* __restrict__ VT)
{
  __shared__ unsigned short tile[64][65];
  const int bh = blockIdx.y, st = blockIdx.x;
  const unsigned short* src = Vrm + (size_t)bh * 65536 + (size_t)st * 64 * 64;
#pragma unroll
  for (int i = 0; i < 16; i++) {
    int idx = i * 256 + threadIdx.x;
    tile[idx >> 6][idx & 63] = src[idx];
  }
  __syncthreads();
  unsigned short* dst = VT + (size_t)bh * 65536 + st * 64;
#pragma unroll
  for (int i = 0; i < 16; i++) {
    int idx = i * 256 + threadIdx.x;
    int dl = idx >> 6, s = idx & 63;
    dst[(size_t)dl * 1024 + s] = tile[s][dl];
  }
}

// ---------------------------------------------------------------- stage 4: causal flash attention
// Block = 4 waves = 64 q-rows (j-th 64-row group); each wave owns a 16-row q-tile.
// All 4 waves iterate the SAME j+1 kv-chunks -> K/V chunk reads L1-hit across waves.
// P staged per-wave in padded LDS (stride 72: conflict-free b128 reads, 2-way writes).
// V loads issued at chunk top; next-chunk K prefetched into a register double buffer.
__global__ __launch_bounds__(256) void attn_kernel(
    const unsigned short* __restrict__ Q, const unsigned short* __restrict__ Kp,
    const unsigned short* __restrict__ VT, unsigned short* __restrict__ Hout)
{
  __shared__ unsigned short P_lds[4][2][16 * 72];
  const int tid = threadIdx.x;
  const int lane = tid & 63, w = tid >> 6;
  const int j = 15 - (int)blockIdx.x;            // reversed: heavy blocks dispatch first
  const int bh = blockIdx.y;
  const int b = bh >> 3, h = bh & 7;
  const int qbase = j * 64 + w * 16;
  const int g = lane >> 4, li = lane & 15;
  const float L2E = 1.44269504088896340736f;
  const int nchunk = j + 1;

  const unsigned short* Qrow = Q + ((size_t)bh * 1024 + qbase) * 64;
  bf16x8 aq0 = *(const bf16x8*)&Qrow[li * 64 + (g << 3)];
  bf16x8 aq1 = *(const bf16x8*)&Qrow[li * 64 + 32 + (g << 3)];

  f32x4 hacc[4];
#pragma unroll
  for (int fj = 0; fj < 4; fj++) hacc[fj] = (f32x4){0.f, 0.f, 0.f, 0.f};
  float mrow[4] = {-1e30f, -1e30f, -1e30f, -1e30f};
  float lrow[4] = {0.f, 0.f, 0.f, 0.f};

  const unsigned short* Kbh = Kp + (size_t)bh * 65536;
  const unsigned short* Vbh = VT + (size_t)bh * 65536;

  bf16x8 bkA[4][2], bkB[4][2];
#pragma unroll
  for (int tt = 0; tt < 4; tt++)
#pragma unroll
    for (int x = 0; x < 2; x++)
      bkA[tt][x] = *(const bf16x8*)&Kbh[(size_t)(tt * 16 + li) * 64 + x * 32 + (g << 3)];

  int c = 0;
  auto body = [&](bf16x8 (&bkC)[4][2], bf16x8 (&bkN)[4][2], unsigned short* pb) {
    const int kv = c * 64;
    // V loads for this chunk — independent, issue before everything else
    bf16x8 bv[4][2];
#pragma unroll
    for (int fj = 0; fj < 4; fj++)
#pragma unroll
      for (int x = 0; x < 2; x++)
        bv[fj][x] = *(const bf16x8*)&Vbh[(size_t)(fj * 16 + li) * 1024 + kv + x * 32 + (g << 3)];

    // QK^T from prefetched K registers
    f32x4 sc[4];
#pragma unroll
    for (int tt = 0; tt < 4; tt++) {
      f32x4 z = (f32x4){0.f, 0.f, 0.f, 0.f};
      z = __builtin_amdgcn_mfma_f32_16x16x32_bf16(aq0, bkC[tt][0], z, 0, 0, 0);
      z = __builtin_amdgcn_mfma_f32_16x16x32_bf16(aq1, bkC[tt][1], z, 0, 0, 0);
      sc[tt] = z;
    }

    // prefetch next chunk's K (uniform branch)
    if (c + 1 < nchunk) {
      const unsigned short* Kn = Kbh + (size_t)(kv + 64) * 64;
#pragma unroll
      for (int tt = 0; tt < 4; tt++)
#pragma unroll
        for (int x = 0; x < 2; x++)
          bkN[tt][x] = *(const bf16x8*)&Kn[(size_t)(tt * 16 + li) * 64 + x * 32 + (g << 3)];
    }

    // scale + (mask only on final chunk) + per-row max
    float rm[4] = {-1e30f, -1e30f, -1e30f, -1e30f};
    if (c == nchunk - 1) {
#pragma unroll
      for (int tt = 0; tt < 4; tt++) {
        int kpos = kv + tt * 16 + li;
#pragma unroll
        for (int r = 0; r < 4; r++) {
          int q = qbase + (g << 2) + r;
          float sv = sc[tt][r] * 0.125f;
          sv = (kpos <= q) ? sv : -1e30f;
          sc[tt][r] = sv;
          rm[r] = fmaxf(rm[r], sv);
        }
      }
    } else {
#pragma unroll
      for (int tt = 0; tt < 4; tt++)
#pragma unroll
        for (int r = 0; r < 4; r++) {
          float sv = sc[tt][r] * 0.125f;
          sc[tt][r] = sv;
          rm[r] = fmaxf(rm[r], sv);
        }
    }
#pragma unroll
    for (int msk = 1; msk < 16; msk <<= 1)
#pragma unroll
      for (int r = 0; r < 4; r++) rm[r] = fmaxf(rm[r], __shfl_xor(rm[r], msk, 64));

    float scl[4];
#pragma unroll
    for (int r = 0; r < 4; r++) {
      float mn = fmaxf(mrow[r], rm[r]);
      scl[r] = exp2f((mrow[r] - mn) * L2E);
      mrow[r] = mn;
      lrow[r] *= scl[r];
    }
#pragma unroll
    for (int fj = 0; fj < 4; fj++)
#pragma unroll
      for (int r = 0; r < 4; r++) hacc[fj][r] *= scl[r];

    float ps[4] = {0.f, 0.f, 0.f, 0.f};
#pragma unroll
    for (int tt = 0; tt < 4; tt++)
#pragma unroll
      for (int r = 0; r < 4; r++) {
        float p = exp2f((sc[tt][r] - mrow[r]) * L2E);
        ps[r] += p;
        pb[((g << 2) + r) * 72 + tt * 16 + li] = f2b(p);
      }
#pragma unroll
    for (int msk = 1; msk < 16; msk <<= 1)
#pragma unroll
      for (int r = 0; r < 4; r++) ps[r] += __shfl_xor(ps[r], msk, 64);
#pragma unroll
    for (int r = 0; r < 4; r++) lrow[r] += ps[r];

    // cross-lane LDS transpose hazard: drain ds ops, pin the point (V/K loads already issued above)
    asm volatile("s_waitcnt lgkmcnt(0)" ::: "memory");
    __builtin_amdgcn_sched_barrier(0);

    bf16x8 ap0 = *(const bf16x8*)&pb[li * 72 + (g << 3)];
    bf16x8 ap1 = *(const bf16x8*)&pb[li * 72 + 32 + (g << 3)];
#pragma unroll
    for (int fj = 0; fj < 4; fj++) {
      hacc[fj] = __builtin_amdgcn_mfma_f32_16x16x32_bf16(ap0, bv[fj][0], hacc[fj], 0, 0, 0);
      hacc[fj] = __builtin_amdgcn_mfma_f32_16x16x32_bf16(ap1, bv[fj][1], hacc[fj], 0, 0, 0);
    }
  };

  unsigned short* pb0 = &P_lds[w][0][0];
  unsigned short* pb1 = &P_lds[w][1][0];
  for (;;) {
    body(bkA, bkB, pb0);
    if (++c == nchunk) break;
    body(bkB, bkA, pb1);
    if (++c == nchunk) break;
  }

  float inv[4];
#pragma unroll
  for (int r = 0; r < 4; r++) inv[r] = 1.0f / lrow[r];
#pragma unroll
  for (int fj = 0; fj < 4; fj++)
#pragma unroll
    for (int r = 0; r < 4; r++) {
      int q = qbase + (g << 2) + r;
      float v = hacc[fj][r] * inv[r];
      Hout[((size_t)b * 1024 + q) * 512 + h * 64 + fj * 16 + li] = f2b(v);
    }
}

// ---------------------------------------------------------------- launch
extern "C" void kernel_launch(void* const* d_in, const int* in_sizes, int n_in,
                              void* d_out, int out_size, void* d_ws, size_t ws_size,
                              hipStream_t stream)
{
  const float* xs  = (const float*)d_in[0];
  const float* xt  = (const float*)d_in[1];
  const float* Wqs = (const float*)d_in[2];
  const float* Wks = (const float*)d_in[3];
  const float* Wvs = (const float*)d_in[4];
  const float* Wqt = (const float*)d_in[5];
  const float* Wkt = (const float*)d_in[6];
  const float* Wvt = (const float*)d_in[7];
  const float* WK  = (const float*)d_in[8];
  const float* Wo  = (const float*)d_in[9];
  float* out = (float*)d_out;

  char* ws = (char*)d_ws;
  unsigned short* Xcat  = (unsigned short*)(ws);             // 16,777,216 B
  unsigned short* Hout  = (unsigned short*)(ws);             // aliases Xcat (dead after gemm<0>)
  unsigned short* WcatT = (unsigned short*)(ws + 16777216);  //  3,145,728 B
  unsigned short* WoT   = (unsigned short*)(ws + 19922944);  //    524,288 B
  float*          WKT   = (float*)         (ws + 20447232);  //    262,144 B
  unsigned short* Qb    = (unsigned short*)(ws + 20709376);  //  8,388,608 B
  unsigned short* Kb    = (unsigned short*)(ws + 29097984);  //  8,388,608 B
  unsigned short* Vrm   = (unsigned short*)(ws + 37486592);  //  8,388,608 B
  unsigned short* VT    = (unsigned short*)(ws + 45875200);  //  8,388,608 B  (total 54,263,808)

  xconvert_kernel<<<4096, 256, 0, stream>>>(xs, xt, Xcat);
  wtrans_kernel<<<dim3(8, 8, 8), 256, 0, stream>>>(Wqs, Wks, Wvs, Wqt, Wkt, Wvt, Wo, WK,
                                                   WcatT, WoT, WKT);
  gemm_bt<0><<<dim3(64, 12), 256, 0, stream>>>(Xcat, WcatT, 1024, nullptr, WKT, Qb, Kb, Vrm);
  vtrans_kernel<<<dim3(16, 64), 256, 0, stream>>>(Vrm, VT);
  attn_kernel<<<dim3(16, 64), 256, 0, stream>>>(Qb, Kb, VT, Hout);
  gemm_bt<1><<<dim3(64, 4), 256, 0, stream>>>(Hout, WoT, 512, out, nullptr, nullptr, nullptr, nullptr);
}

// Round 3
// 204.247 us; speedup vs baseline: 1.4245x; 1.3516x over previous
//
#include <hip/hip_runtime.h>
#include <stdint.h>

// TMSA: two-stream multi-head causal self-attention, MI355X/gfx950.
// B=8 D=512 H=8 IMG=32 -> S=1024, DH=64.
// Pipeline:
//   1a. xconvert: f32->bf16 vectorized pack Xcat[8192][1024]
//   1b. wtrans  : LDS-tiled transposes -> WcatT[1536][1024] bf16, WoT[512][512] bf16,
//                 WKT[1024][64] f32
//   2.  gemm<0> : QKV = Xcat @ Wcat (epilogue scatters per-head, folds WK bias into K,
//                 folds 0.125*log2(e) softmax scale into Q)
//   3.  vtrans  : V row-major -> VT [bh][d][s]
//   4.  attn    : causal flash attention; 4-wave blocks stage K/V chunks in LDS
//                 (global_load_lds + source-side XOR swizzle), mirror-paired q-tiles
//                 (t, 63-t) per wave for uniform work, defer-max, setprio MFMA.
//   5.  gemm<1> : out = H @ Wo (f32 epilogue straight to d_out). Hout aliases Xcat.

typedef __bf16 bf16x8 __attribute__((ext_vector_type(8)));
typedef float  f32x4  __attribute__((ext_vector_type(4)));
typedef unsigned short u16x8 __attribute__((ext_vector_type(8)));

#define DEVI __device__ __forceinline__

DEVI unsigned short f2b(float f) {           // f32 -> bf16, round-nearest-even
  union { float f; unsigned u; } v; v.f = f;
  unsigned u = v.u;
  return (unsigned short)((u + 0x7FFFu + ((u >> 16) & 1u)) >> 16);
}

// ---------------------------------------------------------------- stage 1a: X pack (vectorized)
__global__ __launch_bounds__(256) void xconvert_kernel(
    const float* __restrict__ xs, const float* __restrict__ xt,
    unsigned short* __restrict__ Xcat)
{
  int gid = blockIdx.x * 256 + threadIdx.x;       // 1048576 threads, 8 elems each
  int m = gid >> 7, c0 = (gid & 127) << 3;
  const float* src = (c0 < 512) ? xs + (size_t)m * 512 + c0
                                : xt + (size_t)m * 512 + (c0 - 512);
  float4 a = *(const float4*)src;
  float4 b = *(const float4*)(src + 4);
  u16x8 o;
  o[0] = f2b(a.x); o[1] = f2b(a.y); o[2] = f2b(a.z); o[3] = f2b(a.w);
  o[4] = f2b(b.x); o[5] = f2b(b.y); o[6] = f2b(b.z); o[7] = f2b(b.w);
  *(u16x8*)&Xcat[(size_t)m * 1024 + c0] = o;
}

// ---------------------------------------------------------------- stage 1b: weight transposes
__global__ __launch_bounds__(256) void wtrans_kernel(
    const float* __restrict__ Wqs, const float* __restrict__ Wks, const float* __restrict__ Wvs,
    const float* __restrict__ Wqt, const float* __restrict__ Wkt, const float* __restrict__ Wvt,
    const float* __restrict__ Wo,  const float* __restrict__ WK,
    unsigned short* __restrict__ WcatT, unsigned short* __restrict__ WoT,
    float* __restrict__ WKT)
{
  __shared__ __align__(16) char lds_raw[64 * 65 * 4];
  const int t = threadIdx.x;
  const int r = t >> 2, cb = (t & 3) << 4;
  const int mat = blockIdx.z;

  if (mat < 6) {
    const float* W = (mat == 0) ? Wqs : (mat == 1) ? Wqt : (mat == 2) ? Wks
                   : (mat == 3) ? Wkt : (mat == 4) ? Wvs : Wvt;
    const int ktile = blockIdx.x, ctile = blockIdx.y;
    unsigned short (*tile)[66] = (unsigned short (*)[66])lds_raw;
    const float* src = W + (size_t)(ktile * 64 + r) * 512 + ctile * 64 + cb;
#pragma unroll
    for (int i = 0; i < 4; i++) {
      float4 v = *(const float4*)(src + i * 4);
      tile[r][cb + i * 4 + 0] = f2b(v.x); tile[r][cb + i * 4 + 1] = f2b(v.y);
      tile[r][cb + i * 4 + 2] = f2b(v.z); tile[r][cb + i * 4 + 3] = f2b(v.w);
    }
    __syncthreads();
    const int n = ctile * 64 + r;
    const int sec = mat >> 1, half = mat & 1;
    u16x8 o0, o1;
#pragma unroll
    for (int i = 0; i < 8; i++) { o0[i] = tile[cb + i][r]; o1[i] = tile[cb + 8 + i][r]; }
    unsigned short* dst = WcatT + (size_t)(sec * 512 + n) * 1024 + half * 512 + ktile * 64 + cb;
    *(u16x8*)dst = o0; *(u16x8*)(dst + 8) = o1;
  } else if (mat == 6) {
    const int ktile = blockIdx.x, ctile = blockIdx.y;
    unsigned short (*tile)[66] = (unsigned short (*)[66])lds_raw;
    const float* src = Wo + (size_t)(ktile * 64 + r) * 512 + ctile * 64 + cb;
#pragma unroll
    for (int i = 0; i < 4; i++) {
      float4 v = *(const float4*)(src + i * 4);
      tile[r][cb + i * 4 + 0] = f2b(v.x); tile[r][cb + i * 4 + 1] = f2b(v.y);
      tile[r][cb + i * 4 + 2] = f2b(v.z); tile[r][cb + i * 4 + 3] = f2b(v.w);
    }
    __syncthreads();
    const int n = ctile * 64 + r;
    u16x8 o0, o1;
#pragma unroll
    for (int i = 0; i < 8; i++) { o0[i] = tile[cb + i][r]; o1[i] = tile[cb + 8 + i][r]; }
    unsigned short* dst = WoT + (size_t)n * 512 + ktile * 64 + cb;
    *(u16x8*)dst = o0; *(u16x8*)(dst + 8) = o1;
  } else {
    const int st = blockIdx.y * 8 + blockIdx.x;
    if (st >= 16) return;
    float (*tf)[65] = (float (*)[65])lds_raw;
    const float* src = WK + (size_t)r * 1024 + st * 64 + cb;
#pragma unroll
    for (int i = 0; i < 4; i++) {
      float4 v = *(const float4*)(src + i * 4);
      tf[r][cb + i * 4 + 0] = v.x; tf[r][cb + i * 4 + 1] = v.y;
      tf[r][cb + i * 4 + 2] = v.z; tf[r][cb + i * 4 + 3] = v.w;
    }
    __syncthreads();
    const int s = st * 64 + r;
    float* dst = WKT + (size_t)s * 64 + cb;
#pragma unroll
    for (int i = 0; i < 4; i++) {
      float4 v;
      v.x = tf[cb + i * 4 + 0][r]; v.y = tf[cb + i * 4 + 1][r];
      v.z = tf[cb + i * 4 + 2][r]; v.w = tf[cb + i * 4 + 3][r];
      *(float4*)(dst + i * 4) = v;
    }
  }
}

// ---------------------------------------------------------------- GEMM (A row-major [M,K], BT row-major [N,K])
template <int EPI>
__global__ __launch_bounds__(256) void gemm_bt(
    const unsigned short* __restrict__ A, const unsigned short* __restrict__ BT, int K,
    float* __restrict__ Out, const float* __restrict__ WKT,
    unsigned short* __restrict__ Qb, unsigned short* __restrict__ Kb,
    unsigned short* __restrict__ Vb)
{
  __shared__ unsigned short As[128 * 32];
  __shared__ unsigned short Bs[128 * 32];
  const int t = threadIdx.x;
  const int lane = t & 63, wid = t >> 6;
  const int wr = wid >> 1, wc = wid & 1;
  const int mtile = blockIdx.x, ntile = blockIdx.y;
  const int arow = t >> 2, acol = (t & 3) << 3;
  const int li = lane & 15, g = lane >> 4;

  f32x4 acc[4][4];
#pragma unroll
  for (int i = 0; i < 4; i++)
#pragma unroll
    for (int j = 0; j < 4; j++) acc[i][j] = (f32x4){0.f, 0.f, 0.f, 0.f};

  const unsigned short* aBase = A + (size_t)(mtile * 128 + arow) * K + acol;
  const unsigned short* bBase = BT + (size_t)(ntile * 128 + arow) * K + acol;

  for (int k0 = 0; k0 < K; k0 += 32) {
    __builtin_amdgcn_global_load_lds(
        (__attribute__((address_space(1))) void*)(aBase + k0),
        (__attribute__((address_space(3))) void*)&As[wid * 512], 16, 0, 0);
    __builtin_amdgcn_global_load_lds(
        (__attribute__((address_space(1))) void*)(aBase + (size_t)64 * K + k0),
        (__attribute__((address_space(3))) void*)&As[2048 + wid * 512], 16, 0, 0);
    __builtin_amdgcn_global_load_lds(
        (__attribute__((address_space(1))) void*)(bBase + k0),
        (__attribute__((address_space(3))) void*)&Bs[wid * 512], 16, 0, 0);
    __builtin_amdgcn_global_load_lds(
        (__attribute__((address_space(1))) void*)(bBase + (size_t)64 * K + k0),
        (__attribute__((address_space(3))) void*)&Bs[2048 + wid * 512], 16, 0, 0);
    __syncthreads();

    bf16x8 af[4], bfr[4];
#pragma unroll
    for (int fi = 0; fi < 4; fi++)
      af[fi] = *(const bf16x8*)&As[(wr * 64 + fi * 16 + li) * 32 + (g << 3)];
#pragma unroll
    for (int fj = 0; fj < 4; fj++)
      bfr[fj] = *(const bf16x8*)&Bs[(wc * 64 + fj * 16 + li) * 32 + (g << 3)];
#pragma unroll
    for (int fi = 0; fi < 4; fi++)
#pragma unroll
      for (int fj = 0; fj < 4; fj++)
        acc[fi][fj] = __builtin_amdgcn_mfma_f32_16x16x32_bf16(af[fi], bfr[fj], acc[fi][fj], 0, 0, 0);
    __syncthreads();
  }

  const int lm = g << 2;
  if constexpr (EPI == 0) {
    const float QSCALE = 0.18033688011112042f;  // log2(e)/8 folded into Q
#pragma unroll
    for (int fi = 0; fi < 4; fi++) {
      int mg = mtile * 128 + wr * 64 + fi * 16 + lm;
#pragma unroll
      for (int r = 0; r < 4; r++) {
        int m = mg + r;
        int b = m >> 10, s = m & 1023;
#pragma unroll
        for (int fj = 0; fj < 4; fj++) {
          int n = ntile * 128 + wc * 64 + fj * 16 + li;
          float v = acc[fi][fj][r];
          int sec = n >> 9, nn = n & 511;
          int h = nn >> 6, d = nn & 63;
          size_t o = ((size_t)(b * 8 + h) << 16) + (size_t)s * 64 + d;
          if (sec == 0)      Qb[o] = f2b(v * QSCALE);
          else if (sec == 1) Kb[o] = f2b(v + WKT[(size_t)s * 64 + d]);
          else               Vb[o] = f2b(v);
        }
      }
    }
  } else {
#pragma unroll
    for (int fi = 0; fi < 4; fi++) {
      int mg = mtile * 128 + wr * 64 + fi * 16 + lm;
#pragma unroll
      for (int r = 0; r < 4; r++) {
        size_t m = (size_t)(mg + r);
#pragma unroll
        for (int fj = 0; fj < 4; fj++) {
          int n = ntile * 128 + wc * 64 + fj * 16 + li;
          Out[m * 512 + n] = acc[fi][fj][r];
        }
      }
    }
  }
}

// ---------------------------------------------------------------- stage 3: V [bh][s][d] -> VT [bh][d][s]
__global__ __launch_bounds__(256) void vtrans_kernel(const unsigned short* __restrict__ Vrm,
                                                     unsigned short* __restrict__ VT)
{
  __shared__ unsigned short tile[64][65];
  const int bh = blockIdx.y, st = blockIdx.x;
  const unsigned short* src = Vrm + (size_t)bh * 65536 + (size_t)st * 64 * 64;
#pragma unroll
  for (int i = 0; i < 16; i++) {
    int idx = i * 256 + threadIdx.x;
    tile[idx >> 6][idx & 63] = src[idx];
  }
  __syncthreads();
  unsigned short* dst = VT + (size_t)bh * 65536 + st * 64;
#pragma unroll
  for (int i = 0; i < 16; i++) {
    int idx = i * 256 + threadIdx.x;
    int dl = idx >> 6, s = idx & 63;
    dst[(size_t)dl * 1024 + s] = tile[s][dl];
  }
}

// ---------------------------------------------------------------- stage 4: causal flash attention
// Block = 4 waves; wave w owns mirror-paired 16-row q-tiles (t, 63-t), t = bx*4+w.
// All waves in a block have IDENTICAL trip counts (lo: chunks 0..bx, hi: 0..15-bx).
// K/V chunks staged once per block into LDS via global_load_lds (coalesced) with
// source-side XOR swizzle; fragments read back conflict-free via swizzled ds_read_b128.
// Q is pre-scaled by log2(e)/8 -> scores already in exp2 domain.

#define TILE_A(sc, aq0_, aq1_, mrow, lrow, hacc, ps, pbuf, qb, kvb, isLast)                  \
  {                                                                                          \
    __builtin_amdgcn_s_setprio(1);                                                           \
    _Pragma("unroll")                                                                        \
    for (int tt = 0; tt < 4; tt++) {                                                         \
      f32x4 z = (f32x4){0.f, 0.f, 0.f, 0.f};                                                 \
      z = __builtin_amdgcn_mfma_f32_16x16x32_bf16(aq0_, bk[tt][0], z, 0, 0, 0);              \
      z = __builtin_amdgcn_mfma_f32_16x16x32_bf16(aq1_, bk[tt][1], z, 0, 0, 0);              \
      sc[tt] = z;                                                                            \
    }                                                                                        \
    __builtin_amdgcn_s_setprio(0);                                                           \
    float rm[4] = {-3.0e38f, -3.0e38f, -3.0e38f, -3.0e38f};                                  \
    if (isLast) {                                                                            \
      _Pragma("unroll")                                                                      \
      for (int tt = 0; tt < 4; tt++) {                                                       \
        int kpos = kvb + tt * 16 + li;                                                       \
        _Pragma("unroll")                                                                    \
        for (int r = 0; r < 4; r++) {                                                        \
          float sv = sc[tt][r];                                                              \
          sv = (kpos <= qb + (g << 2) + r) ? sv : -3.0e38f;                                  \
          sc[tt][r] = sv;                                                                    \
          rm[r] = fmaxf(rm[r], sv);                                                          \
        }                                                                                    \
      }                                                                                      \
    } else {                                                                                 \
      _Pragma("unroll")                                                                      \
      for (int tt = 0; tt < 4; tt++)                                                         \
        _Pragma("unroll")                                                                    \
        for (int r = 0; r < 4; r++) rm[r] = fmaxf(rm[r], sc[tt][r]);                         \
    }                                                                                        \
    _Pragma("unroll")                                                                        \
    for (int msk = 1; msk < 16; msk <<= 1)                                                   \
      _Pragma("unroll")                                                                      \
      for (int r = 0; r < 4; r++) rm[r] = fmaxf(rm[r], __shfl_xor(rm[r], msk, 64));          \
    int ok_ = 1;                                                                             \
    _Pragma("unroll")                                                                        \
    for (int r = 0; r < 4; r++) ok_ &= (rm[r] <= mrow[r] + 8.0f);                            \
    if (!__all(ok_)) {                                                                       \
      _Pragma("unroll")                                                                      \
      for (int r = 0; r < 4; r++) {                                                          \
        float mn = fmaxf(mrow[r], rm[r]);                                                    \
        float scl = exp2f(mrow[r] - mn);                                                     \
        mrow[r] = mn; lrow[r] *= scl;                                                        \
        _Pragma("unroll")                                                                    \
        for (int fj = 0; fj < 4; fj++) hacc[fj][r] *= scl;                                   \
      }                                                                                      \
    }                                                                                        \
    _Pragma("unroll")                                                                        \
    for (int r = 0; r < 4; r++) ps[r] = 0.f;                                                 \
    _Pragma("unroll")                                                                        \
    for (int tt = 0; tt < 4; tt++)                                                           \
      _Pragma("unroll")                                                                      \
      for (int r = 0; r < 4; r++) {                                                          \
        float p = exp2f(sc[tt][r] - mrow[r]);                                                \
        ps[r] += p;                                                                          \
        pbuf[((g << 2) + r) * 72 + tt * 16 + li] = f2b(p);                                   \
      }                                                                                      \
  }

#define TILE_B(hacc, ps, lrow, pbuf)                                                         \
  {                                                                                          \
    bf16x8 ap0 = *(const bf16x8*)&pbuf[li * 72 + (g << 3)];                                  \
    bf16x8 ap1 = *(const bf16x8*)&pbuf[li * 72 + 32 + (g << 3)];                             \
    __builtin_amdgcn_s_setprio(1);                                                           \
    _Pragma("unroll")                                                                        \
    for (int fj = 0; fj < 4; fj++) {                                                         \
      hacc[fj] = __builtin_amdgcn_mfma_f32_16x16x32_bf16(ap0, bv[fj][0], hacc[fj], 0, 0, 0); \
      hacc[fj] = __builtin_amdgcn_mfma_f32_16x16x32_bf16(ap1, bv[fj][1], hacc[fj], 0, 0, 0); \
    }                                                                                        \
    __builtin_amdgcn_s_setprio(0);                                                           \
    _Pragma("unroll")                                                                        \
    for (int msk = 1; msk < 16; msk <<= 1)                                                   \
      _Pragma("unroll")                                                                      \
      for (int r = 0; r < 4; r++) ps[r] += __shfl_xor(ps[r], msk, 64);                       \
    _Pragma("unroll")                                                                        \
    for (int r = 0; r < 4; r++) lrow[r] += ps[r];                                            \
  }

__global__ __launch_bounds__(256) void attn_kernel(
    const unsigned short* __restrict__ Q, const unsigned short* __restrict__ Kp,
    const unsigned short* __restrict__ VT, unsigned short* __restrict__ Hout)
{
  __shared__ unsigned short Ksm[2][4096];   // [buf][row*64 + swizzled 8-elem slots]
  __shared__ unsigned short Vsm[2][4096];
  __shared__ unsigned short P_lds[4][2][16 * 72];

  const int tid = threadIdx.x;
  const int lane = tid & 63, w = tid >> 6;
  const int bx = blockIdx.x;                // 0..7
  const int bh = blockIdx.y;
  const int b = bh >> 3, h = bh & 7;
  const int tl = bx * 4 + w;                // lo tile 0..31
  const int th = 63 - tl;                   // hi tile 32..63
  const int qlo = tl * 16, qhi = th * 16;
  const int clo = bx;                       // lo tile's last chunk
  const int cmax = 15 - bx;                 // hi tile's last chunk
  const int g = lane >> 4, li = lane & 15;

  const unsigned short* Kbh = Kp + (size_t)bh * 65536;
  const unsigned short* Vbh = VT + (size_t)bh * 65536;

  // stage chunk c into buffer bf: K rows s (contiguous), V rows d (128B segments),
  // global source pre-swizzled so linear LDS + swizzled reads = conflict-free.
  auto STAGE = [&](int c, int bf) {
    int j0 = tid, j1 = tid + 256;
    int r0 = j0 >> 3, s0 = (j0 & 7) ^ (r0 & 7);
    int r1 = j1 >> 3, s1 = (j1 & 7) ^ (r1 & 7);
    __builtin_amdgcn_global_load_lds(
        (const __attribute__((address_space(1))) void*)(Kbh + (size_t)(c * 64 + r0) * 64 + s0 * 8),
        (__attribute__((address_space(3))) void*)&Ksm[bf][w * 512], 16, 0, 0);
    __builtin_amdgcn_global_load_lds(
        (const __attribute__((address_space(1))) void*)(Kbh + (size_t)(c * 64 + r1) * 64 + s1 * 8),
        (__attribute__((address_space(3))) void*)&Ksm[bf][2048 + w * 512], 16, 0, 0);
    __builtin_amdgcn_global_load_lds(
        (const __attribute__((address_space(1))) void*)(Vbh + (size_t)r0 * 1024 + c * 64 + s0 * 8),
        (__attribute__((address_space(3))) void*)&Vsm[bf][w * 512], 16, 0, 0);
    __builtin_amdgcn_global_load_lds(
        (const __attribute__((address_space(1))) void*)(Vbh + (size_t)r1 * 1024 + c * 64 + s1 * 8),
        (__attribute__((address_space(3))) void*)&Vsm[bf][2048 + w * 512], 16, 0, 0);
  };

  const unsigned short* QL = Q + ((size_t)bh * 1024 + qlo) * 64;
  const unsigned short* QH = Q + ((size_t)bh * 1024 + qhi) * 64;
  bf16x8 aqL0 = *(const bf16x8*)&QL[li * 64 + (g << 3)];
  bf16x8 aqL1 = *(const bf16x8*)&QL[li * 64 + 32 + (g << 3)];
  bf16x8 aqH0 = *(const bf16x8*)&QH[li * 64 + (g << 3)];
  bf16x8 aqH1 = *(const bf16x8*)&QH[li * 64 + 32 + (g << 3)];

  f32x4 haccL[4], haccH[4];
#pragma unroll
  for (int fj = 0; fj < 4; fj++) {
    haccL[fj] = (f32x4){0.f, 0.f, 0.f, 0.f};
    haccH[fj] = (f32x4){0.f, 0.f, 0.f, 0.f};
  }
  float mrowL[4] = {-3.0e38f, -3.0e38f, -3.0e38f, -3.0e38f};
  float mrowH[4] = {-3.0e38f, -3.0e38f, -3.0e38f, -3.0e38f};
  float lrowL[4] = {0.f, 0.f, 0.f, 0.f};
  float lrowH[4] = {0.f, 0.f, 0.f, 0.f};

  unsigned short* pbL = &P_lds[w][0][0];
  unsigned short* pbH = &P_lds[w][1][0];

  STAGE(0, 0);
  __syncthreads();

  for (int c = 0; c <= cmax; c++) {
    const int cur = c & 1;
    if (c < cmax) STAGE(c + 1, cur ^ 1);

    // K fragments (swizzled read, conflict-free)
    bf16x8 bk[4][2];
#pragma unroll
    for (int tt = 0; tt < 4; tt++) {
      int s = tt * 16 + li;
#pragma unroll
      for (int x2 = 0; x2 < 2; x2++)
        bk[tt][x2] = *(const bf16x8*)&Ksm[cur][s * 64 + (((g + 4 * x2) ^ (s & 7)) << 3)];
    }

    const int kvb = c * 64;
    const int loAct = (c <= clo);
    float psL[4], psH[4];
    f32x4 scL[4], scH[4];

    if (loAct) TILE_A(scL, aqL0, aqL1, mrowL, lrowL, haccL, psL, pbL, qlo, kvb, (c == clo));
    TILE_A(scH, aqH0, aqH1, mrowH, lrowH, haccH, psH, pbH, qhi, kvb, (c == cmax));

    // cross-lane LDS transpose hazard: drain ds ops before fragment reads (rule #18)
    asm volatile("s_waitcnt lgkmcnt(0)" ::: "memory");
    __builtin_amdgcn_sched_barrier(0);

    // V fragments (swizzled read)
    bf16x8 bv[4][2];
#pragma unroll
    for (int fj = 0; fj < 4; fj++) {
      int d = fj * 16 + li;
#pragma unroll
      for (int x2 = 0; x2 < 2; x2++)
        bv[fj][x2] = *(const bf16x8*)&Vsm[cur][d * 64 + (((g + 4 * x2) ^ (d & 7)) << 3)];
    }

    if (loAct) TILE_B(haccL, psL, lrowL, pbL);
    TILE_B(haccH, psH, lrowH, pbH);

    __syncthreads();   // next buffer staged + all waves done with current
  }

  float invL[4], invH[4];
#pragma unroll
  for (int r = 0; r < 4; r++) { invL[r] = 1.0f / lrowL[r]; invH[r] = 1.0f / lrowH[r]; }
#pragma unroll
  for (int fj = 0; fj < 4; fj++)
#pragma unroll
    for (int r = 0; r < 4; r++) {
      int qL = qlo + (g << 2) + r;
      int qH = qhi + (g << 2) + r;
      Hout[((size_t)b * 1024 + qL) * 512 + h * 64 + fj * 16 + li] = f2b(haccL[fj][r] * invL[r]);
      Hout[((size_t)b * 1024 + qH) * 512 + h * 64 + fj * 16 + li] = f2b(haccH[fj][r] * invH[r]);
    }
}

// ---------------------------------------------------------------- launch
extern "C" void kernel_launch(void* const* d_in, const int* in_sizes, int n_in,
                              void* d_out, int out_size, void* d_ws, size_t ws_size,
                              hipStream_t stream)
{
  const float* xs  = (const float*)d_in[0];
  const float* xt  = (const float*)d_in[1];
  const float* Wqs = (const float*)d_in[2];
  const float* Wks = (const float*)d_in[3];
  const float* Wvs = (const float*)d_in[4];
  const float* Wqt = (const float*)d_in[5];
  const float* Wkt = (const float*)d_in[6];
  const float* Wvt = (const float*)d_in[7];
  const float* WK  = (const float*)d_in[8];
  const float* Wo  = (const float*)d_in[9];
  float* out = (float*)d_out;

  char* ws = (char*)d_ws;
  unsigned short* Xcat  = (unsigned short*)(ws);             // 16,777,216 B
  unsigned short* Hout  = (unsigned short*)(ws);             // aliases Xcat (dead after gemm<0>)
  unsigned short* WcatT = (unsigned short*)(ws + 16777216);  //  3,145,728 B
  unsigned short* WoT   = (unsigned short*)(ws + 19922944);  //    524,288 B
  float*          WKT   = (float*)         (ws + 20447232);  //    262,144 B
  unsigned short* Qb    = (unsigned short*)(ws + 20709376);  //  8,388,608 B
  unsigned short* Kb    = (unsigned short*)(ws + 29097984);  //  8,388,608 B
  unsigned short* Vrm   = (unsigned short*)(ws + 37486592);  //  8,388,608 B
  unsigned short* VT    = (unsigned short*)(ws + 45875200);  //  8,388,608 B  (total 54,263,808)

  xconvert_kernel<<<4096, 256, 0, stream>>>(xs, xt, Xcat);
  wtrans_kernel<<<dim3(8, 8, 8), 256, 0, stream>>>(Wqs, Wks, Wvs, Wqt, Wkt, Wvt, Wo, WK,
                                                   WcatT, WoT, WKT);
  gemm_bt<0><<<dim3(64, 12), 256, 0, stream>>>(Xcat, WcatT, 1024, nullptr, WKT, Qb, Kb, Vrm);
  vtrans_kernel<<<dim3(16, 64), 256, 0, stream>>>(Vrm, VT);
  attn_kernel<<<dim3(8, 64), 256, 0, stream>>>(Qb, Kb, VT, Hout);
  gemm_bt<1><<<dim3(64, 4), 256, 0, stream>>>(Hout, WoT, 512, out, nullptr, nullptr, nullptr, nullptr);
}

// Round 5
// 191.193 us; speedup vs baseline: 1.5217x; 1.0683x over previous
//
#include <hip/hip_runtime.h>
#include <stdint.h>

// TMSA: two-stream multi-head causal self-attention, MI355X/gfx950.
// B=8 D=512 H=8 IMG=32 -> S=1024, DH=64.
// Pipeline:
//   1a. xconvert: f32->bf16 vectorized pack Xcat[8192][1024]
//   1b. wtrans  : LDS-tiled transposes -> WcatT[1536][1024] bf16, WoT[512][512] bf16,
//                 WKT[1024][64] f32
//   2.  gemm<0> : QKV = Xcat @ Wcat. 2-phase prefetch double-buffered LDS (T3-minimum),
//                 one barrier/K-step. Epilogue: block-uniform section dispatch,
//                 folds WK bias into K and log2(e)/8 into Q.
//   3.  vtrans  : V row-major -> VT [bh][d][s]
//   4.  attn    : causal flash attention; 4-wave blocks stage K/V chunks in LDS
//                 (global_load_lds + source-side XOR swizzle), mirror-paired q-tiles.
//   5.  gemm<1> : out = H @ Wo (f32 epilogue straight to d_out). Hout aliases Xcat.

typedef __bf16 bf16x8 __attribute__((ext_vector_type(8)));
typedef float  f32x4  __attribute__((ext_vector_type(4)));
typedef unsigned short u16x8 __attribute__((ext_vector_type(8)));

#define DEVI __device__ __forceinline__

DEVI unsigned short f2b(float f) {           // f32 -> bf16, round-nearest-even
  union { float f; unsigned u; } v; v.f = f;
  unsigned u = v.u;
  return (unsigned short)((u + 0x7FFFu + ((u >> 16) & 1u)) >> 16);
}

// ---------------------------------------------------------------- stage 1a: X pack (vectorized)
__global__ __launch_bounds__(256) void xconvert_kernel(
    const float* __restrict__ xs, const float* __restrict__ xt,
    unsigned short* __restrict__ Xcat)
{
  int gid = blockIdx.x * 256 + threadIdx.x;       // 1048576 threads, 8 elems each
  int m = gid >> 7, c0 = (gid & 127) << 3;
  const float* src = (c0 < 512) ? xs + (size_t)m * 512 + c0
                                : xt + (size_t)m * 512 + (c0 - 512);
  float4 a = *(const float4*)src;
  float4 b = *(const float4*)(src + 4);
  u16x8 o;
  o[0] = f2b(a.x); o[1] = f2b(a.y); o[2] = f2b(a.z); o[3] = f2b(a.w);
  o[4] = f2b(b.x); o[5] = f2b(b.y); o[6] = f2b(b.z); o[7] = f2b(b.w);
  *(u16x8*)&Xcat[(size_t)m * 1024 + c0] = o;
}

// ---------------------------------------------------------------- stage 1b: weight transposes
__global__ __launch_bounds__(256) void wtrans_kernel(
    const float* __restrict__ Wqs, const float* __restrict__ Wks, const float* __restrict__ Wvs,
    const float* __restrict__ Wqt, const float* __restrict__ Wkt, const float* __restrict__ Wvt,
    const float* __restrict__ Wo,  const float* __restrict__ WK,
    unsigned short* __restrict__ WcatT, unsigned short* __restrict__ WoT,
    float* __restrict__ WKT)
{
  __shared__ __align__(16) char lds_raw[64 * 65 * 4];
  const int t = threadIdx.x;
  const int r = t >> 2, cb = (t & 3) << 4;
  const int mat = blockIdx.z;

  if (mat < 6) {
    const float* W = (mat == 0) ? Wqs : (mat == 1) ? Wqt : (mat == 2) ? Wks
                   : (mat == 3) ? Wkt : (mat == 4) ? Wvs : Wvt;
    const int ktile = blockIdx.x, ctile = blockIdx.y;
    unsigned short (*tile)[66] = (unsigned short (*)[66])lds_raw;
    const float* src = W + (size_t)(ktile * 64 + r) * 512 + ctile * 64 + cb;
#pragma unroll
    for (int i = 0; i < 4; i++) {
      float4 v = *(const float4*)(src + i * 4);
      tile[r][cb + i * 4 + 0] = f2b(v.x); tile[r][cb + i * 4 + 1] = f2b(v.y);
      tile[r][cb + i * 4 + 2] = f2b(v.z); tile[r][cb + i * 4 + 3] = f2b(v.w);
    }
    __syncthreads();
    const int n = ctile * 64 + r;
    const int sec = mat >> 1, half = mat & 1;
    u16x8 o0, o1;
#pragma unroll
    for (int i = 0; i < 8; i++) { o0[i] = tile[cb + i][r]; o1[i] = tile[cb + 8 + i][r]; }
    unsigned short* dst = WcatT + (size_t)(sec * 512 + n) * 1024 + half * 512 + ktile * 64 + cb;
    *(u16x8*)dst = o0; *(u16x8*)(dst + 8) = o1;
  } else if (mat == 6) {
    const int ktile = blockIdx.x, ctile = blockIdx.y;
    unsigned short (*tile)[66] = (unsigned short (*)[66])lds_raw;
    const float* src = Wo + (size_t)(ktile * 64 + r) * 512 + ctile * 64 + cb;
#pragma unroll
    for (int i = 0; i < 4; i++) {
      float4 v = *(const float4*)(src + i * 4);
      tile[r][cb + i * 4 + 0] = f2b(v.x); tile[r][cb + i * 4 + 1] = f2b(v.y);
      tile[r][cb + i * 4 + 2] = f2b(v.z); tile[r][cb + i * 4 + 3] = f2b(v.w);
    }
    __syncthreads();
    const int n = ctile * 64 + r;
    u16x8 o0, o1;
#pragma unroll
    for (int i = 0; i < 8; i++) { o0[i] = tile[cb + i][r]; o1[i] = tile[cb + 8 + i][r]; }
    unsigned short* dst = WoT + (size_t)n * 512 + ktile * 64 + cb;
    *(u16x8*)dst = o0; *(u16x8*)(dst + 8) = o1;
  } else {
    const int st = blockIdx.y * 8 + blockIdx.x;
    if (st >= 16) return;
    float (*tf)[65] = (float (*)[65])lds_raw;
    const float* src = WK + (size_t)r * 1024 + st * 64 + cb;
#pragma unroll
    for (int i = 0; i < 4; i++) {
      float4 v = *(const float4*)(src + i * 4);
      tf[r][cb + i * 4 + 0] = v.x; tf[r][cb + i * 4 + 1] = v.y;
      tf[r][cb + i * 4 + 2] = v.z; tf[r][cb + i * 4 + 3] = v.w;
    }
    __syncthreads();
    const int s = st * 64 + r;
    float* dst = WKT + (size_t)s * 64 + cb;
#pragma unroll
    for (int i = 0; i < 4; i++) {
      float4 v;
      v.x = tf[cb + i * 4 + 0][r]; v.y = tf[cb + i * 4 + 1][r];
      v.z = tf[cb + i * 4 + 2][r]; v.w = tf[cb + i * 4 + 3][r];
      *(float4*)(dst + i * 4) = v;
    }
  }
}

// ---------------------------------------------------------------- GEMM (A row-major [M,K], BT row-major [N,K])
// 128x128 tile, BK=32, 4 waves 2x2, 4x4 frags of 16x16x32 per wave.
// 2-phase: STAGE(k+1) issued BEFORE consuming tile k; ONE barrier per K-step
// (its implicit vmcnt(0) drains the prefetch that has been in flight under the MFMAs).
template <int EPI>
__global__ __launch_bounds__(256) void gemm_bt(
    const unsigned short* __restrict__ A, const unsigned short* __restrict__ BT, int K,
    float* __restrict__ Out, const float* __restrict__ WKT,
    unsigned short* __restrict__ Qb, unsigned short* __restrict__ Kb,
    unsigned short* __restrict__ Vb)
{
  __shared__ unsigned short As[2][128 * 32];
  __shared__ unsigned short Bs[2][128 * 32];
  const int t = threadIdx.x;
  const int lane = t & 63, wid = t >> 6;
  const int wr = wid >> 1, wc = wid & 1;
  const int mtile = blockIdx.x, ntile = blockIdx.y;
  const int arow = t >> 2, acol = (t & 3) << 3;
  const int li = lane & 15, g = lane >> 4;

  f32x4 acc[4][4];
#pragma unroll
  for (int i = 0; i < 4; i++)
#pragma unroll
    for (int j = 0; j < 4; j++) acc[i][j] = (f32x4){0.f, 0.f, 0.f, 0.f};

  const unsigned short* aBase = A + (size_t)(mtile * 128 + arow) * K + acol;
  const unsigned short* bBase = BT + (size_t)(ntile * 128 + arow) * K + acol;

  auto STAGE = [&](int k0, int bf) {
    __builtin_amdgcn_global_load_lds(
        (const __attribute__((address_space(1))) void*)(aBase + k0),
        (__attribute__((address_space(3))) void*)&As[bf][wid * 512], 16, 0, 0);
    __builtin_amdgcn_global_load_lds(
        (const __attribute__((address_space(1))) void*)(aBase + (size_t)64 * K + k0),
        (__attribute__((address_space(3))) void*)&As[bf][2048 + wid * 512], 16, 0, 0);
    __builtin_amdgcn_global_load_lds(
        (const __attribute__((address_space(1))) void*)(bBase + k0),
        (__attribute__((address_space(3))) void*)&Bs[bf][wid * 512], 16, 0, 0);
    __builtin_amdgcn_global_load_lds(
        (const __attribute__((address_space(1))) void*)(bBase + (size_t)64 * K + k0),
        (__attribute__((address_space(3))) void*)&Bs[bf][2048 + wid * 512], 16, 0, 0);
  };

  STAGE(0, 0);
  __syncthreads();

  int cur = 0;
  for (int k0 = 0; k0 < K; k0 += 32) {
    if (k0 + 32 < K) STAGE(k0 + 32, cur ^ 1);   // in flight under this step's MFMAs

    bf16x8 af[4], bfr[4];
#pragma unroll
    for (int fi = 0; fi < 4; fi++)
      af[fi] = *(const bf16x8*)&As[cur][(wr * 64 + fi * 16 + li) * 32 + (g << 3)];
#pragma unroll
    for (int fj = 0; fj < 4; fj++)
      bfr[fj] = *(const bf16x8*)&Bs[cur][(wc * 64 + fj * 16 + li) * 32 + (g << 3)];
    __builtin_amdgcn_s_setprio(1);
#pragma unroll
    for (int fi = 0; fi < 4; fi++)
#pragma unroll
      for (int fj = 0; fj < 4; fj++)
        acc[fi][fj] = __builtin_amdgcn_mfma_f32_16x16x32_bf16(af[fi], bfr[fj], acc[fi][fj], 0, 0, 0);
    __builtin_amdgcn_s_setprio(0);
    __syncthreads();
    cur ^= 1;
  }

  const int lm = g << 2;
  if constexpr (EPI == 0) {
    const float QSCALE = 0.18033688011112042f;  // log2(e)/8 folded into Q
    const int sec = ntile >> 2;                 // block-uniform: 128-tile within one 512-section
#pragma unroll
    for (int fi = 0; fi < 4; fi++) {
      int mg = mtile * 128 + wr * 64 + fi * 16 + lm;
#pragma unroll
      for (int r = 0; r < 4; r++) {
        int m = mg + r;
        int b = m >> 10, s = m & 1023;
        size_t rowo = ((size_t)b * 8) << 16;
        if (sec == 0) {
#pragma unroll
          for (int fj = 0; fj < 4; fj++) {
            int nn = (ntile & 3) * 128 + wc * 64 + fj * 16 + li;
            ((__bf16*)Qb)[rowo + ((size_t)(nn >> 6) << 16) + (size_t)s * 64 + (nn & 63)] =
                (__bf16)(acc[fi][fj][r] * QSCALE);
          }
        } else if (sec == 1) {
#pragma unroll
          for (int fj = 0; fj < 4; fj++) {
            int nn = (ntile & 3) * 128 + wc * 64 + fj * 16 + li;
            int d = nn & 63;
            ((__bf16*)Kb)[rowo + ((size_t)(nn >> 6) << 16) + (size_t)s * 64 + d] =
                (__bf16)(acc[fi][fj][r] + WKT[(size_t)s * 64 + d]);
          }
        } else {
#pragma unroll
          for (int fj = 0; fj < 4; fj++) {
            int nn = (ntile & 3) * 128 + wc * 64 + fj * 16 + li;
            ((__bf16*)Vb)[rowo + ((size_t)(nn >> 6) << 16) + (size_t)s * 64 + (nn & 63)] =
                (__bf16)acc[fi][fj][r];
          }
        }
      }
    }
  } else {
#pragma unroll
    for (int fi = 0; fi < 4; fi++) {
      int mg = mtile * 128 + wr * 64 + fi * 16 + lm;
#pragma unroll
      for (int r = 0; r < 4; r++) {
        size_t m = (size_t)(mg + r);
#pragma unroll
        for (int fj = 0; fj < 4; fj++) {
          int n = ntile * 128 + wc * 64 + fj * 16 + li;
          Out[m * 512 + n] = acc[fi][fj][r];
        }
      }
    }
  }
}

// ---------------------------------------------------------------- stage 3: V [bh][s][d] -> VT [bh][d][s]
__global__ __launch_bounds__(256) void vtrans_kernel(const unsigned short* __restrict__ Vrm,
                                                     unsigned short* __restrict__ VT)
{
  __shared__ unsigned short tile[64][65];
  const int bh = blockIdx.y, st = blockIdx.x;
  const unsigned short* src = Vrm + (size_t)bh * 65536 + (size_t)st * 64 * 64;
#pragma unroll
  for (int i = 0; i < 16; i++) {
    int idx = i * 256 + threadIdx.x;
    tile[idx >> 6][idx & 63] = src[idx];
  }
  __syncthreads();
  unsigned short* dst = VT + (size_t)bh * 65536 + st * 64;
#pragma unroll
  for (int i = 0; i < 16; i++) {
    int idx = i * 256 + threadIdx.x;
    int dl = idx >> 6, s = idx & 63;
    dst[(size_t)dl * 1024 + s] = tile[s][dl];
  }
}

// ---------------------------------------------------------------- stage 4: causal flash attention
// Block = 4 waves; wave w owns mirror-paired 16-row q-tiles (t, 63-t), t = bx*4+w.
// All waves in a block have IDENTICAL trip counts (lo: chunks 0..bx, hi: 0..15-bx).
// K/V chunks staged once per block into LDS via global_load_lds (coalesced) with
// source-side XOR swizzle; fragments read back conflict-free via swizzled ds_read_b128.
// Q is pre-scaled by log2(e)/8 -> scores already in exp2 domain.

#define TILE_A(sc, aq0_, aq1_, mrow, lrow, hacc, ps, pbuf, qb, kvb, isLast)                  \
  {                                                                                          \
    __builtin_amdgcn_s_setprio(1);                                                           \
    _Pragma("unroll")                                                                        \
    for (int tt = 0; tt < 4; tt++) {                                                         \
      f32x4 z = (f32x4){0.f, 0.f, 0.f, 0.f};                                                 \
      z = __builtin_amdgcn_mfma_f32_16x16x32_bf16(aq0_, bk[tt][0], z, 0, 0, 0);              \
      z = __builtin_amdgcn_mfma_f32_16x16x32_bf16(aq1_, bk[tt][1], z, 0, 0, 0);              \
      sc[tt] = z;                                                                            \
    }                                                                                        \
    __builtin_amdgcn_s_setprio(0);                                                           \
    float rm[4] = {-3.0e38f, -3.0e38f, -3.0e38f, -3.0e38f};                                  \
    if (isLast) {                                                                            \
      _Pragma("unroll")                                                                      \
      for (int tt = 0; tt < 4; tt++) {                                                       \
        int kpos = kvb + tt * 16 + li;                                                       \
        _Pragma("unroll")                                                                    \
        for (int r = 0; r < 4; r++) {                                                        \
          float sv = sc[tt][r];                                                              \
          sv = (kpos <= qb + (g << 2) + r) ? sv : -3.0e38f;                                  \
          sc[tt][r] = sv;                                                                    \
          rm[r] = fmaxf(rm[r], sv);                                                          \
        }                                                                                    \
      }                                                                                      \
    } else {                                                                                 \
      _Pragma("unroll")                                                                      \
      for (int tt = 0; tt < 4; tt++)                                                         \
        _Pragma("unroll")                                                                    \
        for (int r = 0; r < 4; r++) rm[r] = fmaxf(rm[r], sc[tt][r]);                         \
    }                                                                                        \
    _Pragma("unroll")                                                                        \
    for (int msk = 1; msk < 16; msk <<= 1)                                                   \
      _Pragma("unroll")                                                                      \
      for (int r = 0; r < 4; r++) rm[r] = fmaxf(rm[r], __shfl_xor(rm[r], msk, 64));          \
    int ok_ = 1;                                                                             \
    _Pragma("unroll")                                                                        \
    for (int r = 0; r < 4; r++) ok_ &= (rm[r] <= mrow[r] + 8.0f);                            \
    if (!__all(ok_)) {                                                                       \
      _Pragma("unroll")                                                                      \
      for (int r = 0; r < 4; r++) {                                                          \
        float mn = fmaxf(mrow[r], rm[r]);                                                    \
        float scl = exp2f(mrow[r] - mn);                                                     \
        mrow[r] = mn; lrow[r] *= scl;                                                        \
        _Pragma("unroll")                                                                    \
        for (int fj = 0; fj < 4; fj++) hacc[fj][r] *= scl;                                   \
      }                                                                                      \
    }                                                                                        \
    _Pragma("unroll")                                                                        \
    for (int r = 0; r < 4; r++) ps[r] = 0.f;                                                 \
    _Pragma("unroll")                                                                        \
    for (int tt = 0; tt < 4; tt++)                                                           \
      _Pragma("unroll")                                                                      \
      for (int r = 0; r < 4; r++) {                                                          \
        float p = exp2f(sc[tt][r] - mrow[r]);                                                \
        ps[r] += p;                                                                          \
        pbuf[((g << 2) + r) * 72 + tt * 16 + li] = f2b(p);                                   \
      }                                                                                      \
  }

#define TILE_B(hacc, ps, lrow, pbuf)                                                         \
  {                                                                                          \
    bf16x8 ap0 = *(const bf16x8*)&pbuf[li * 72 + (g << 3)];                                  \
    bf16x8 ap1 = *(const bf16x8*)&pbuf[li * 72 + 32 + (g << 3)];                             \
    __builtin_amdgcn_s_setprio(1);                                                           \
    _Pragma("unroll")                                                                        \
    for (int fj = 0; fj < 4; fj++) {                                                         \
      hacc[fj] = __builtin_amdgcn_mfma_f32_16x16x32_bf16(ap0, bv[fj][0], hacc[fj], 0, 0, 0); \
      hacc[fj] = __builtin_amdgcn_mfma_f32_16x16x32_bf16(ap1, bv[fj][1], hacc[fj], 0, 0, 0); \
    }                                                                                        \
    __builtin_amdgcn_s_setprio(0);                                                           \
    _Pragma("unroll")                                                                        \
    for (int msk = 1; msk < 16; msk <<= 1)                                                   \
      _Pragma("unroll")                                                                      \
      for (int r = 0; r < 4; r++) ps[r] += __shfl_xor(ps[r], msk, 64);                       \
    _Pragma("unroll")                                                                        \
    for (int r = 0; r < 4; r++) lrow[r] += ps[r];                                            \
  }

__global__ __launch_bounds__(256) void attn_kernel(
    const unsigned short* __restrict__ Q, const unsigned short* __restrict__ Kp,
    const unsigned short* __restrict__ VT, unsigned short* __restrict__ Hout)
{
  __shared__ unsigned short Ksm[2][4096];   // [buf][row*64 + swizzled 8-elem slots]
  __shared__ unsigned short Vsm[2][4096];
  __shared__ unsigned short P_lds[4][2][16 * 72];

  const int tid = threadIdx.x;
  const int lane = tid & 63, w = tid >> 6;
  const int bx = blockIdx.x;                // 0..7
  const int bh = blockIdx.y;
  const int b = bh >> 3, h = bh & 7;
  const int tl = bx * 4 + w;                // lo tile 0..31
  const int th = 63 - tl;                   // hi tile 32..63
  const int qlo = tl * 16, qhi = th * 16;
  const int clo = bx;                       // lo tile's last chunk
  const int cmax = 15 - bx;                 // hi tile's last chunk
  const int g = lane >> 4, li = lane & 15;

  const unsigned short* Kbh = Kp + (size_t)bh * 65536;
  const unsigned short* Vbh = VT + (size_t)bh * 65536;

  auto STAGE = [&](int c, int bf) {
    int j0 = tid, j1 = tid + 256;
    int r0 = j0 >> 3, s0 = (j0 & 7) ^ (r0 & 7);
    int r1 = j1 >> 3, s1 = (j1 & 7) ^ (r1 & 7);
    __builtin_amdgcn_global_load_lds(
        (const __attribute__((address_space(1))) void*)(Kbh + (size_t)(c * 64 + r0) * 64 + s0 * 8),
        (__attribute__((address_space(3))) void*)&Ksm[bf][w * 512], 16, 0, 0);
    __builtin_amdgcn_global_load_lds(
        (const __attribute__((address_space(1))) void*)(Kbh + (size_t)(c * 64 + r1) * 64 + s1 * 8),
        (__attribute__((address_space(3))) void*)&Ksm[bf][2048 + w * 512], 16, 0, 0);
    __builtin_amdgcn_global_load_lds(
        (const __attribute__((address_space(1))) void*)(Vbh + (size_t)r0 * 1024 + c * 64 + s0 * 8),
        (__attribute__((address_space(3))) void*)&Vsm[bf][w * 512], 16, 0, 0);
    __builtin_amdgcn_global_load_lds(
        (const __attribute__((address_space(1))) void*)(Vbh + (size_t)r1 * 1024 + c * 64 + s1 * 8),
        (__attribute__((address_space(3))) void*)&Vsm[bf][2048 + w * 512], 16, 0, 0);
  };

  const unsigned short* QL = Q + ((size_t)bh * 1024 + qlo) * 64;
  const unsigned short* QH = Q + ((size_t)bh * 1024 + qhi) * 64;
  bf16x8 aqL0 = *(const bf16x8*)&QL[li * 64 + (g << 3)];
  bf16x8 aqL1 = *(const bf16x8*)&QL[li * 64 + 32 + (g << 3)];
  bf16x8 aqH0 = *(const bf16x8*)&QH[li * 64 + (g << 3)];
  bf16x8 aqH1 = *(const bf16x8*)&QH[li * 64 + 32 + (g << 3)];

  f32x4 haccL[4], haccH[4];
#pragma unroll
  for (int fj = 0; fj < 4; fj++) {
    haccL[fj] = (f32x4){0.f, 0.f, 0.f, 0.f};
    haccH[fj] = (f32x4){0.f, 0.f, 0.f, 0.f};
  }
  float mrowL[4] = {-3.0e38f, -3.0e38f, -3.0e38f, -3.0e38f};
  float mrowH[4] = {-3.0e38f, -3.0e38f, -3.0e38f, -3.0e38f};
  float lrowL[4] = {0.f, 0.f, 0.f, 0.f};
  float lrowH[4] = {0.f, 0.f, 0.f, 0.f};

  unsigned short* pbL = &P_lds[w][0][0];
  unsigned short* pbH = &P_lds[w][1][0];

  STAGE(0, 0);
  __syncthreads();

  for (int c = 0; c <= cmax; c++) {
    const int cur = c & 1;
    if (c < cmax) STAGE(c + 1, cur ^ 1);

    bf16x8 bk[4][2];
#pragma unroll
    for (int tt = 0; tt < 4; tt++) {
      int s = tt * 16 + li;
#pragma unroll
      for (int x2 = 0; x2 < 2; x2++)
        bk[tt][x2] = *(const bf16x8*)&Ksm[cur][s * 64 + (((g + 4 * x2) ^ (s & 7)) << 3)];
    }

    const int kvb = c * 64;
    const int loAct = (c <= clo);
    float psL[4], psH[4];
    f32x4 scL[4], scH[4];

    if (loAct) TILE_A(scL, aqL0, aqL1, mrowL, lrowL, haccL, psL, pbL, qlo, kvb, (c == clo));
    TILE_A(scH, aqH0, aqH1, mrowH, lrowH, haccH, psH, pbH, qhi, kvb, (c == cmax));

    asm volatile("s_waitcnt lgkmcnt(0)" ::: "memory");
    __builtin_amdgcn_sched_barrier(0);

    bf16x8 bv[4][2];
#pragma unroll
    for (int fj = 0; fj < 4; fj++) {
      int d = fj * 16 + li;
#pragma unroll
      for (int x2 = 0; x2 < 2; x2++)
        bv[fj][x2] = *(const bf16x8*)&Vsm[cur][d * 64 + (((g + 4 * x2) ^ (d & 7)) << 3)];
    }

    if (loAct) TILE_B(haccL, psL, lrowL, pbL);
    TILE_B(haccH, psH, lrowH, pbH);

    __syncthreads();
  }

  float invL[4], invH[4];
#pragma unroll
  for (int r = 0; r < 4; r++) { invL[r] = 1.0f / lrowL[r]; invH[r] = 1.0f / lrowH[r]; }
#pragma unroll
  for (int fj = 0; fj < 4; fj++)
#pragma unroll
    for (int r = 0; r < 4; r++) {
      int qL = qlo + (g << 2) + r;
      int qH = qhi + (g << 2) + r;
      Hout[((size_t)b * 1024 + qL) * 512 + h * 64 + fj * 16 + li] = f2b(haccL[fj][r] * invL[r]);
      Hout[((size_t)b * 1024 + qH) * 512 + h * 64 + fj * 16 + li] = f2b(haccH[fj][r] * invH[r]);
    }
}

// ---------------------------------------------------------------- launch
extern "C" void kernel_launch(void* const* d_in, const int* in_sizes, int n_in,
                              void* d_out, int out_size, void* d_ws, size_t ws_size,
                              hipStream_t stream)
{
  const float* xs  = (const float*)d_in[0];
  const float* xt  = (const float*)d_in[1];
  const float* Wqs = (const float*)d_in[2];
  const float* Wks = (const float*)d_in[3];
  const float* Wvs = (const float*)d_in[4];
  const float* Wqt = (const float*)d_in[5];
  const float* Wkt = (const float*)d_in[6];
  const float* Wvt = (const float*)d_in[7];
  const float* WK  = (const float*)d_in[8];
  const float* Wo  = (const float*)d_in[9];
  float* out = (float*)d_out;

  char* ws = (char*)d_ws;
  unsigned short* Xcat  = (unsigned short*)(ws);             // 16,777,216 B
  unsigned short* Hout  = (unsigned short*)(ws);             // aliases Xcat (dead after gemm<0>)
  unsigned short* WcatT = (unsigned short*)(ws + 16777216);  //  3,145,728 B
  unsigned short* WoT   = (unsigned short*)(ws + 19922944);  //    524,288 B
  float*          WKT   = (float*)         (ws + 20447232);  //    262,144 B
  unsigned short* Qb    = (unsigned short*)(ws + 20709376);  //  8,388,608 B
  unsigned short* Kb    = (unsigned short*)(ws + 29097984);  //  8,388,608 B
  unsigned short* Vrm   = (unsigned short*)(ws + 37486592);  //  8,388,608 B
  unsigned short* VT    = (unsigned short*)(ws + 45875200);  //  8,388,608 B  (total 54,263,808)

  xconvert_kernel<<<4096, 256, 0, stream>>>(xs, xt, Xcat);
  wtrans_kernel<<<dim3(8, 8, 8), 256, 0, stream>>>(Wqs, Wks, Wvs, Wqt, Wkt, Wvt, Wo, WK,
                                                   WcatT, WoT, WKT);
  gemm_bt<0><<<dim3(64, 12), 256, 0, stream>>>(Xcat, WcatT, 1024, nullptr, WKT, Qb, Kb, Vrm);
  vtrans_kernel<<<dim3(16, 64), 256, 0, stream>>>(Vrm, VT);
  attn_kernel<<<dim3(8, 64), 256, 0, stream>>>(Qb, Kb, VT, Hout);
  gemm_bt<1><<<dim3(64, 4), 256, 0, stream>>>(Hout, WoT, 512, out, nullptr, nullptr, nullptr, nullptr);
}